// Round 23
// baseline (797.516 us; speedup 1.0000x reference)
//
#include <hip/hip_runtime.h>
#include <math.h>

#define NR 8192
#define NPICK 4096
#define SDF_THR_C 5e-5f

// output layout (floats)
#define OUT_DPRED 0
#define OUT_SDFL  8192
#define OUT_SAMP  16384
#define OUT_FIN   139264   // 16384 + 40960*3

typedef __attribute__((ext_vector_type(8))) short short8v;
typedef __attribute__((ext_vector_type(4))) float f32x4;

#define SK  320   // activation plane k-stride (shorts)
#define SKB 640   // bytes per plane row

struct Wptrs { const float* w[8]; };
struct EvalP {
  const float* b[8];
  const float* b8;
  const unsigned short* WTi;   // fragment-major: [g][ks][hi 512s | lo 512s]
  const float* w8c;
  const float* ray0; const float* rdir;
  float* tminA; float* tmaxA;
  float* nextS; float* nextE;
  int* mselS; int* mselE; int* mcarS; int* mcarE;
  float* accS; float* accE;
  float* strack; float* ptrack; float* evalpts;
};

__device__ __forceinline__ unsigned short f2bf(float f) {
  unsigned int u = __float_as_uint(f);
  unsigned int r = u + 0x7FFFu + ((u >> 16) & 1u);
  return (unsigned short)(r >> 16);
}
__device__ __forceinline__ float bf2f(unsigned short h) {
  return __uint_as_float(((unsigned int)h) << 16);
}
// Fast softplus (validated round 9, absmax 0.0156). Embed trig stays EXACT
// sinf/cosf (the risky part of the round-4 failure).
__device__ __forceinline__ float softplus100(float h) {
  float z = 100.0f * h;
  return (fmaxf(z, 0.0f) + __logf(1.0f + __expf(-fabsf(z)))) * 0.01f;
}

// ---------------------------------------------------------------------------
// prep: transpose + bf16 hi/lo split, FRAGMENT-MAJOR layout (r21 big win)
// ---------------------------------------------------------------------------
__global__ void prep_transpose(Wptrs wp, unsigned short* __restrict__ WTi)
{
  __shared__ unsigned short sh[64 * 66];
  __shared__ unsigned short sl[64 * 66];
  const int Kreal[8] = {39,256,256,256,295,256,256,256};
  const int Kp[8]    = {64,256,256,256,320,256,256,256};
  const int WB[8]    = {0,16384,81920,147456,212992,294912,360448,425984};
  const int cum[9]   = {0,4,20,36,52,72,88,104,120};
  int b = blockIdx.x;
  int l = 0;
  while (l < 7 && b >= cum[l + 1]) ++l;
  int tile = b - cum[l];
  int tk_n = Kp[l] >> 6;
  int tk = tile % tk_n, tc = tile / tk_n;
  const float* __restrict__ W = wp.w[l];
  int t = threadIdx.x;
  #pragma unroll
  for (int i = 0; i < 16; ++i) {
    int id = t + i * 256;
    int kl = id >> 6, cl = id & 63;
    int k = tk * 64 + kl, c = tc * 64 + cl;
    float v = (k < Kreal[l]) ? W[k * 256 + c] : 0.0f;
    unsigned short h = f2bf(v);
    unsigned short lo = f2bf(v - bf2f(h));
    sh[kl * 66 + cl] = h;
    sl[kl * 66 + cl] = lo;
  }
  __syncthreads();
  const int nksL = Kp[l] >> 5;
  #pragma unroll
  for (int i = 0; i < 16; ++i) {
    int id = t + i * 256;
    int cl = id >> 6, kl = id & 63;
    int col = tc * 64 + cl;
    int k = tk * 64 + kl;
    int g = col >> 4, lr = col & 15;
    int ksg = k >> 5, lq = (k >> 3) & 3, e = k & 7;
    int lane = lq * 16 + lr;
    size_t base = 2 * (size_t)WB[l] + ((size_t)(g * nksL + ksg)) * 1024 + lane * 8 + e;
    WTi[base]       = sh[kl * 66 + cl];
    WTi[base + 512] = sl[kl * 66 + cl];
  }
}

__global__ void prep_w8(const float* __restrict__ w8, float* __restrict__ w8c)
{
  int t = threadIdx.x;
  w8c[t] = w8[(size_t)t * 257];   // column 0 of (256,257)
}

// ---------------------------------------------------------------------------
// One layer, 2x2 tile (wave = 2 row-tiles x 2 col-groups; halves per-CU LDS
// A-read traffic vs 4x1 — viable now that B is fragment-major coalesced).
// Rotating 2-deep B-prefetch for both groups.
// Per-(row,col) MFMA chain (hh,lh,hl per ks) identical -> bit-identical.
// ---------------------------------------------------------------------------
template<int NKS>
__device__ __forceinline__ void layer_2x2(
    const unsigned short* __restrict__ wt, const float* __restrict__ bias,
    unsigned short* Ah, unsigned short* Al,
    int lq, int lr, int rtb, int cw, int swA)
{
  const char* ahc = (const char*)Ah;
  const char* alc = (const char*)Al;
  f32x4 acc[2][2];
  #pragma unroll
  for (int i = 0; i < 2; ++i)
    #pragma unroll
    for (int j = 0; j < 2; ++j)
      acc[i][j] = (f32x4){0.f, 0.f, 0.f, 0.f};

  const int lane_off = (lq * 16 + lr) * 8;
  const unsigned short* wg[2];
  wg[0] = wt + (size_t)((cw >> 4) + 0) * NKS * 1024 + lane_off;
  wg[1] = wt + (size_t)((cw >> 4) + 1) * NKS * 1024 + lane_off;

  short8v Bh[2][2], Bl[2][2];   // [buf][ct]
  #pragma unroll
  for (int ct = 0; ct < 2; ++ct) {
    Bh[0][ct] = *(const short8v*)(wg[ct]);
    Bl[0][ct] = *(const short8v*)(wg[ct] + 512);
  }

  #pragma unroll
  for (int ks = 0; ks < NKS; ++ks) {
    const int cur = ks & 1, nxt = cur ^ 1;
    if (ks + 1 < NKS) {
      #pragma unroll
      for (int ct = 0; ct < 2; ++ct) {
        const unsigned short* wn = wg[ct] + (size_t)(ks + 1) * 1024;
        Bh[nxt][ct] = *(const short8v*)(wn);
        Bl[nxt][ct] = *(const short8v*)(wn + 512);
      }
    }
    int ax = (ks * 64 + lq * 16) ^ swA;
    short8v ah[2], al[2];
    #pragma unroll
    for (int rt = 0; rt < 2; ++rt) {
      ah[rt] = *(const short8v*)(ahc + ((rtb + rt) * 16 + lr) * SKB + ax);
      al[rt] = *(const short8v*)(alc + ((rtb + rt) * 16 + lr) * SKB + ax);
    }
    #pragma unroll
    for (int ct = 0; ct < 2; ++ct) {
      #pragma unroll
      for (int rt = 0; rt < 2; ++rt) {
        acc[rt][ct] = __builtin_amdgcn_mfma_f32_16x16x32_bf16(ah[rt], Bh[cur][ct], acc[rt][ct], 0, 0, 0);
        acc[rt][ct] = __builtin_amdgcn_mfma_f32_16x16x32_bf16(al[rt], Bh[cur][ct], acc[rt][ct], 0, 0, 0);
        acc[rt][ct] = __builtin_amdgcn_mfma_f32_16x16x32_bf16(ah[rt], Bl[cur][ct], acc[rt][ct], 0, 0, 0);
      }
    }
  }

  __syncthreads();   // all plane reads of this layer complete

  char* ahw = (char*)Ah;
  char* alw = (char*)Al;
  #pragma unroll
  for (int ct = 0; ct < 2; ++ct) {
    int col = cw + ct * 16 + lr;
    float bv = bias[col];
    int cb2 = col * 2;
    #pragma unroll
    for (int rt = 0; rt < 2; ++rt) {
      #pragma unroll
      for (int r = 0; r < 4; ++r) {
        float h = softplus100(acc[rt][ct][r] + bv);
        unsigned short hh = f2bf(h);
        unsigned short hl = f2bf(h - bf2f(hh));
        int row = (rtb + rt) * 16 + lq * 4 + r;
        int addr = row * SKB + (cb2 ^ ((row & 7) << 4));
        *(unsigned short*)(ahw + addr) = hh;
        *(unsigned short*)(alw + addr) = hl;
      }
    }
  }
  __syncthreads();
}

// ---------------------------------------------------------------------------
// Fused eval+march. 64 rows = 32 rays/block (rows 0-31 = s, 32-63 = e);
// 1024 threads, 16 waves each owning a 2x2 tile block. r22 structure
// otherwise verbatim (parallel embed, march tail on threads 0-31).
// ---------------------------------------------------------------------------
__global__ __launch_bounds__(1024, 1)
void eval_fused(EvalP P, int tstep)
{
  __shared__ __align__(16) unsigned short Ah[64 * SK];   // 40 KB
  __shared__ __align__(16) unsigned short Al[64 * SK];   // 40 KB
  __shared__ float enc[64 * 40];                         // 10 KB
  __shared__ float red[8 * 64];                          // 2 KB
  __shared__ float sdfv[64];
  const int WBA[8] = {0,16384,81920,147456,212992,294912,360448,425984};

  const int t = threadIdx.x;
  const int rayb = blockIdx.x * 32;

  // ---- embed part 1: normalized coords (192 threads, 64 rows x 3)
  if (t < 192) {
    int row = t / 3, c = t - row * 3;
    int idx = (row < 32) ? (rayb + row) : (NR + rayb + row - 32);
    float p = P.evalpts[3 * idx + c];
    enc[row * 40 + c] = ((p + 1.0f) * 0.5f) * 2.0f - 1.0f;
  }
  __syncthreads();
  // ---- embed part 2: 64 rows x 36 trig over all 1024 threads (exact
  // sinf/cosf; arg = xn * 2^lf — identical product to the serial version)
  for (int i = t; i < 64 * 36; i += 1024) {
    int row = i / 36, j = i - row * 36;
    int jj = (j < 18) ? j : j - 18;
    int c = jj % 3, lf = jj / 3;
    float arg = enc[row * 40 + c] * (float)(1 << lf);
    enc[row * 40 + 3 + j] = (j < 18) ? sinf(arg) : cosf(arg);
  }
  __syncthreads();

  // ---- scatter enc (bf16 hi/lo) to planes: k in [0,64) and [256,320)
  {
    char* ahp = (char*)Ah;
    char* alp = (char*)Al;
    int row = t >> 4, c4 = t & 15;   // 64 rows x 16 chunks of 4 k
    int sw = (row & 7) << 4;
    #pragma unroll
    for (int reg = 0; reg < 2; ++reg) {
      int koff = reg ? 256 : 0;
      #pragma unroll
      for (int e = 0; e < 4; e += 2) {
        int kl = c4 * 4 + e;
        float v0 = (kl     < 39) ? enc[row * 40 + kl]     : 0.0f;
        float v1 = (kl + 1 < 39) ? enc[row * 40 + kl + 1] : 0.0f;
        unsigned short h0 = f2bf(v0), h1 = f2bf(v1);
        unsigned short q0 = f2bf(v0 - bf2f(h0)), q1 = f2bf(v1 - bf2f(h1));
        int addr = row * SKB + (((koff + kl) * 2) ^ sw);
        *(unsigned int*)(ahp + addr) = (unsigned)h0 | ((unsigned)h1 << 16);
        *(unsigned int*)(alp + addr) = (unsigned)q0 | ((unsigned)q1 << 16);
      }
    }
  }
  __syncthreads();

  const int lane = t & 63, wv = t >> 6;   // 16 waves
  const int lq = lane >> 4, lr = lane & 15;
  const int rtb = (wv & 1) * 2;           // row-tile pair base (0 or 2)
  const int cw  = (wv >> 1) * 32;         // col pair base (0..224)
  const char* ahc = (const char*)Ah;
  const int swA = (lr & 7) << 4;

  // ---- layers 0..7
  layer_2x2<2>(P.WTi + 2 * (size_t)WBA[0], P.b[0], Ah, Al, lq, lr, rtb, cw, swA);
  #pragma unroll 1
  for (int l = 1; l < 8; ++l) {
    if (l == 4)
      layer_2x2<10>(P.WTi + 2 * (size_t)WBA[4], P.b[4], Ah, Al, lq, lr, rtb, cw, swA);
    else
      layer_2x2<8>(P.WTi + 2 * (size_t)WBA[l], P.b[l], Ah, Al, lq, lr, rtb, cw, swA);
  }

  // ---- layer 8: column 0 only; 8x32-k partition + part-ascending reduce
  {
    const char* alc = (const char*)Al;
    if (t < 512) {
      int row = t & 63, part = t >> 6;
      int sw = (row & 7) << 4;
      float s = 0.0f;
      #pragma unroll
      for (int c = 0; c < 4; ++c) {
        int k = part * 32 + c * 8;
        int addr = row * SKB + ((k * 2) ^ sw);
        short8v vh = *(const short8v*)(ahc + addr);
        short8v vl = *(const short8v*)(alc + addr);
        #pragma unroll
        for (int e = 0; e < 8; ++e) {
          float h = bf2f((unsigned short)vh[e]) + bf2f((unsigned short)vl[e]);
          s = fmaf(h, P.w8c[k + e], s);
        }
      }
      red[part * 64 + row] = s;
    }
    __syncthreads();
    if (t < 64) {
      float tot = P.b8[0];
      #pragma unroll
      for (int p = 0; p < 8; ++p) tot += red[p * 64 + t];
      sdfv[t] = tot;
    }
    __syncthreads();
  }

  // ---- march tail (march_kernel body verbatim; threads 0-31)
  if (t < 32) {
    int r = rayb + t;
    float tmn = P.tminA[r], tmx = P.tmaxA[r];
    float rs = sdfv[t], re = sdfv[32 + t];
    float ns, ne, as_, ae; int ms, me;
    if (tstep == 0) {
      ns = rs; ne = re; ms = 1; me = 1; as_ = tmn; ae = tmx;
    } else {
      ns = P.nextS[r]; ne = P.nextE[r];
      ns = P.mselS[r] ? rs : ns;       // selection deferred from step t-1
      ne = P.mselE[r] ? re : ne;
      ms = P.mcarS[r]; me = P.mcarE[r];
      as_ = P.accS[r]; ae = P.accE[r];
    }
    P.strack[r*8 + tstep] = rs;        // sdf_tracks[:, t] = unmasked s-eval
    float cs = (fabsf(ns) <= SDF_THR_C) ? 0.0f : ns;
    float ce = (fabsf(ne) <= SDF_THR_C) ? 0.0f : ne;
    ms = ms & ((fabsf(cs) > SDF_THR_C) ? 1 : 0);
    me = me & ((fabsf(ce) > SDF_THR_C) ? 1 : 0);
    as_ = fminf(as_ + cs, tmx);
    ae  = fminf(ae + ce, tmx);
    if (tstep < 7) {
      float ox = P.ray0[3*r], oy = P.ray0[3*r+1], oz = P.ray0[3*r+2];
      float dx = P.rdir[3*r], dy = P.rdir[3*r+1], dz = P.rdir[3*r+2];
      float px = ox + as_*dx, py = oy + as_*dy, pz = oz + as_*dz;
      float qx = ox + ae*dx,  qy = oy + ae*dy,  qz = oz + ae*dz;
      P.ptrack[r*24 + (tstep+1)*3 + 0] = px;
      P.ptrack[r*24 + (tstep+1)*3 + 1] = py;
      P.ptrack[r*24 + (tstep+1)*3 + 2] = pz;
      P.evalpts[3*r+0] = px; P.evalpts[3*r+1] = py; P.evalpts[3*r+2] = pz;
      P.evalpts[3*(NR+r)+0] = qx; P.evalpts[3*(NR+r)+1] = qy; P.evalpts[3*(NR+r)+2] = qz;
    }
    int ok = (as_ < ae) ? 1 : 0;
    P.mselS[r] = ms;       P.mselE[r] = me;       // pre-ok (select) masks
    P.mcarS[r] = ms & ok;  P.mcarE[r] = me & ok;  // carry masks
    P.nextS[r] = ns; P.nextE[r] = ne;
    P.accS[r] = as_; P.accE[r] = ae;
  }
}

// ---------------------------------------------------------------------------
// init: ray-AABB, initial points
// ---------------------------------------------------------------------------
__global__ void init_kernel(const float* __restrict__ ray0, const float* __restrict__ rdir,
                            float* tminA, float* tmaxA, float* evalpts, float* ptrack)
{
  int r = blockIdx.x * 256 + threadIdx.x;
  if (r >= NR) return;
  float ox = ray0[3*r], oy = ray0[3*r+1], oz = ray0[3*r+2];
  float dx = rdir[3*r], dy = rdir[3*r+1], dz = rdir[3*r+2];
  float ix = 1.0f/dx, iy = 1.0f/dy, iz = 1.0f/dz;
  float t1x = (-1.0f - ox)*ix, t2x = (1.0f - ox)*ix;
  float t1y = (-1.0f - oy)*iy, t2y = (1.0f - oy)*iy;
  float t1z = (-1.0f - oz)*iz, t2z = (1.0f - oz)*iz;
  float tmn = fmaxf(fmaxf(fminf(t1x,t2x), fminf(t1y,t2y)), fminf(t1z,t2z));
  float tmx = fminf(fminf(fmaxf(t1x,t2x), fmaxf(t1y,t2y)), fmaxf(t1z,t2z));
  tmn = fmaxf(tmn, 0.0f);
  tminA[r] = tmn; tmaxA[r] = tmx;
  float px = ox + tmn*dx, py = oy + tmn*dy, pz = oz + tmn*dz;
  float qx = ox + tmx*dx, qy = oy + tmx*dy, qz = oz + tmx*dz;
  evalpts[3*r+0] = px; evalpts[3*r+1] = py; evalpts[3*r+2] = pz;
  evalpts[3*(NR+r)+0] = qx; evalpts[3*(NR+r)+1] = qy; evalpts[3*(NR+r)+2] = qz;
  ptrack[r*24+0] = px; ptrack[r*24+1] = py; ptrack[r*24+2] = pz;
}

// ---------------------------------------------------------------------------
// finalize: outputs
// ---------------------------------------------------------------------------
__global__ void finalize_kernel(const float* __restrict__ ray0, const float* __restrict__ rdir,
                                const float* __restrict__ frand, const int* __restrict__ pick,
                                const float* __restrict__ strack, const float* __restrict__ ptrack,
                                const float* __restrict__ accE,
                                const float* __restrict__ tminA, const float* __restrict__ tmaxA,
                                float* __restrict__ out)
{
  int r = blockIdx.x * 256 + threadIdx.x;
  if (r < NR) {
    float tmn = tminA[r], tmx = tmaxA[r];
    float sum = 0.f;
    #pragma unroll
    for (int tt = 0; tt < 8; ++tt) sum += strack[r*8 + tt];
    out[OUT_DPRED + r] = fminf(sum + tmn, tmx);
    float last = strack[r*8 + 7];
    out[OUT_SDFL + r] = last;
    out[OUT_FIN + r] = (fabsf(last) < 0.0015625f) ? 1.0f : 0.0f;
    float du = fminf(1.5f * accE[r], tmx);
    float fr = frand[r];
    float dsm = (1.0f - fr) * du + fr * tmn;
    float ox = ray0[3*r], oy = ray0[3*r+1], oz = ray0[3*r+2];
    float dx = rdir[3*r], dy = rdir[3*r+1], dz = rdir[3*r+2];
    int o2 = OUT_SAMP + 98304 + 3*r;
    out[o2+0] = ox + dsm*dx;
    out[o2+1] = oy + dsm*dy;
    out[o2+2] = oz + dsm*dz;
  }
  if (r < NPICK) {
    int ray = pick[r];
    #pragma unroll
    for (int i = 0; i < 24; ++i)
      out[OUT_SAMP + r*24 + i] = ptrack[ray*24 + i];
  }
}

// ---------------------------------------------------------------------------
extern "C" void kernel_launch(void* const* d_in, const int* in_sizes, int n_in,
                              void* d_out, int out_size, void* d_ws, size_t ws_size,
                              hipStream_t stream)
{
  const float* ray0  = (const float*)d_in[0];
  const float* rdir  = (const float*)d_in[1];
  const float* frand = (const float*)d_in[2];
  const int*   pick  = (const int*)d_in[3];
  Wptrs wp;
  EvalP ep;
  for (int i = 0; i < 8; ++i) {
    wp.w[i] = (const float*)d_in[4 + 2*i];
    ep.b[i] = (const float*)d_in[5 + 2*i];
  }
  const float* w8 = (const float*)d_in[20];
  ep.b8 = (const float*)d_in[21];
  ep.ray0 = ray0; ep.rdir = rdir;

  float* ws = (float*)d_ws;
  float* evalpts = ws;                 // 49152
  float* tminA   = evalpts + 49152;
  float* tmaxA   = tminA + 8192;
  float* nextS   = tmaxA + 8192;
  float* nextE   = nextS + 8192;
  float* accS    = nextE + 8192;
  float* accE    = accS + 8192;
  float* strack  = accE + 8192;        // 65536
  float* ptrack  = strack + 65536;     // 196608
  int*   mselS   = (int*)(ptrack + 196608);
  int*   mselE   = mselS + 8192;
  int*   mcarS   = mselE + 8192;
  int*   mcarE   = mcarS + 8192;
  float* w8c     = (float*)(mcarE + 8192);
  unsigned short* WTi = (unsigned short*)(w8c + 256);   // 983040 shorts fragment-major
  ep.WTi = WTi; ep.w8c = w8c;
  ep.tminA = tminA; ep.tmaxA = tmaxA;
  ep.nextS = nextS; ep.nextE = nextE;
  ep.mselS = mselS; ep.mselE = mselE; ep.mcarS = mcarS; ep.mcarE = mcarE;
  ep.accS = accS; ep.accE = accE;
  ep.strack = strack; ep.ptrack = ptrack; ep.evalpts = evalpts;
  float* out = (float*)d_out;

  prep_transpose<<<120, 256, 0, stream>>>(wp, WTi);
  prep_w8<<<1, 256, 0, stream>>>(w8, w8c);
  init_kernel<<<NR/256, 256, 0, stream>>>(ray0, rdir, tminA, tmaxA, evalpts, ptrack);
  for (int t = 0; t < 8; ++t)
    eval_fused<<<NR/32, 1024, 0, stream>>>(ep, t);
  finalize_kernel<<<NR/256, 256, 0, stream>>>(ray0, rdir, frand, pick,
                                              strack, ptrack, accE, tminA, tmaxA, out);
}

// Round 24
// 541.325 us; speedup vs baseline: 1.4733x; 1.4733x over previous
//
#include <hip/hip_runtime.h>
#include <math.h>

#define NR 8192
#define NPICK 4096
#define SDF_THR_C 5e-5f

// output layout (floats)
#define OUT_DPRED 0
#define OUT_SDFL  8192
#define OUT_SAMP  16384
#define OUT_FIN   139264   // 16384 + 40960*3

typedef __attribute__((ext_vector_type(8))) short short8v;
typedef __attribute__((ext_vector_type(4))) float f32x4;

#define SK  320   // activation plane k-stride (shorts)
#define SKB 640   // bytes per plane row

struct Wptrs { const float* w[8]; };
struct EvalP {
  const float* b[8];
  const float* b8;
  const unsigned short* WTi;   // fragment-major: [g][ks][hi 512s | lo 512s]
  const float* w8c;
  const float* ray0; const float* rdir;
  float* tminA; float* tmaxA;
  float* nextS; float* nextE;
  int* mselS; int* mselE; int* mcarS; int* mcarE;
  float* accS; float* accE;
  float* strack; float* ptrack; float* evalpts;
};

__device__ __forceinline__ unsigned short f2bf(float f) {
  unsigned int u = __float_as_uint(f);
  unsigned int r = u + 0x7FFFu + ((u >> 16) & 1u);
  return (unsigned short)(r >> 16);
}
__device__ __forceinline__ float bf2f(unsigned short h) {
  return __uint_as_float(((unsigned int)h) << 16);
}
// Fast softplus (validated round 9, absmax 0.0156). Embed trig stays EXACT
// sinf/cosf (the risky part of the round-4 failure).
__device__ __forceinline__ float softplus100(float h) {
  float z = 100.0f * h;
  return (fmaxf(z, 0.0f) + __logf(1.0f + __expf(-fabsf(z)))) * 0.01f;
}

// ---------------------------------------------------------------------------
// prep: transpose + bf16 hi/lo split, FRAGMENT-MAJOR layout (r21 big win)
// ---------------------------------------------------------------------------
__global__ void prep_transpose(Wptrs wp, unsigned short* __restrict__ WTi)
{
  __shared__ unsigned short sh[64 * 66];
  __shared__ unsigned short sl[64 * 66];
  const int Kreal[8] = {39,256,256,256,295,256,256,256};
  const int Kp[8]    = {64,256,256,256,320,256,256,256};
  const int WB[8]    = {0,16384,81920,147456,212992,294912,360448,425984};
  const int cum[9]   = {0,4,20,36,52,72,88,104,120};
  int b = blockIdx.x;
  int l = 0;
  while (l < 7 && b >= cum[l + 1]) ++l;
  int tile = b - cum[l];
  int tk_n = Kp[l] >> 6;
  int tk = tile % tk_n, tc = tile / tk_n;
  const float* __restrict__ W = wp.w[l];
  int t = threadIdx.x;
  #pragma unroll
  for (int i = 0; i < 16; ++i) {
    int id = t + i * 256;
    int kl = id >> 6, cl = id & 63;
    int k = tk * 64 + kl, c = tc * 64 + cl;
    float v = (k < Kreal[l]) ? W[k * 256 + c] : 0.0f;
    unsigned short h = f2bf(v);
    unsigned short lo = f2bf(v - bf2f(h));
    sh[kl * 66 + cl] = h;
    sl[kl * 66 + cl] = lo;
  }
  __syncthreads();
  const int nksL = Kp[l] >> 5;
  #pragma unroll
  for (int i = 0; i < 16; ++i) {
    int id = t + i * 256;
    int cl = id >> 6, kl = id & 63;
    int col = tc * 64 + cl;
    int k = tk * 64 + kl;
    int g = col >> 4, lr = col & 15;
    int ksg = k >> 5, lq = (k >> 3) & 3, e = k & 7;
    int lane = lq * 16 + lr;
    size_t base = 2 * (size_t)WB[l] + ((size_t)(g * nksL + ksg)) * 1024 + lane * 8 + e;
    WTi[base]       = sh[kl * 66 + cl];
    WTi[base + 512] = sl[kl * 66 + cl];
  }
}

// ---------------------------------------------------------------------------
// One layer, r17 tile (wave = 4 row-tiles x 1 col-tile), rotating 2-deep
// B-prefetch, fragment-major coalesced B (r21/r22 core — unchanged).
// ---------------------------------------------------------------------------
template<int NKS, int KPL>
__device__ __forceinline__ void layer_bpre(
    const unsigned short* __restrict__ wt, const float* __restrict__ bias,
    unsigned short* Ah, unsigned short* Al,
    int lq, int lr, int cw, int swA)
{
  const char* ahc = (const char*)Ah;
  const char* alc = (const char*)Al;
  f32x4 acc[4];
  #pragma unroll
  for (int i = 0; i < 4; ++i) acc[i] = (f32x4){0.f, 0.f, 0.f, 0.f};

  const int col = cw + lr;
  const unsigned short* wcol = wt + (size_t)(cw >> 4) * NKS * 1024 + (lq * 16 + lr) * 8;

  short8v Bh[2], Bl[2];
  Bh[0] = *(const short8v*)(wcol);
  Bl[0] = *(const short8v*)(wcol + 512);

  #pragma unroll
  for (int ks = 0; ks < NKS; ++ks) {
    const int cur = ks & 1, nxt = cur ^ 1;
    if (ks + 1 < NKS) {
      const unsigned short* wn = wcol + (size_t)(ks + 1) * 1024;
      Bh[nxt] = *(const short8v*)(wn);
      Bl[nxt] = *(const short8v*)(wn + 512);
    }
    int ax = (ks * 64 + lq * 16) ^ swA;
    short8v ah[4], al[4];
    #pragma unroll
    for (int rt = 0; rt < 4; ++rt) {
      ah[rt] = *(const short8v*)(ahc + (rt * 16 + lr) * SKB + ax);
      al[rt] = *(const short8v*)(alc + (rt * 16 + lr) * SKB + ax);
    }
    #pragma unroll
    for (int rt = 0; rt < 4; ++rt) {
      acc[rt] = __builtin_amdgcn_mfma_f32_16x16x32_bf16(ah[rt], Bh[cur], acc[rt], 0, 0, 0);
      acc[rt] = __builtin_amdgcn_mfma_f32_16x16x32_bf16(al[rt], Bh[cur], acc[rt], 0, 0, 0);
      acc[rt] = __builtin_amdgcn_mfma_f32_16x16x32_bf16(ah[rt], Bl[cur], acc[rt], 0, 0, 0);
    }
  }

  __syncthreads();   // all plane reads of this layer complete

  char* ahw = (char*)Ah;
  char* alw = (char*)Al;
  {
    float bv = bias[col];
    int cb2 = col * 2;
    #pragma unroll
    for (int rt = 0; rt < 4; ++rt) {
      #pragma unroll
      for (int r = 0; r < 4; ++r) {
        float h = softplus100(acc[rt][r] + bv);
        unsigned short hh = f2bf(h);
        unsigned short hl = f2bf(h - bf2f(hh));
        int row = rt * 16 + lq * 4 + r;
        int addr = row * SKB + (cb2 ^ ((row & 7) << 4));
        *(unsigned short*)(ahw + addr) = hh;
        *(unsigned short*)(alw + addr) = hl;
      }
    }
  }
  __syncthreads();
}

// ---------------------------------------------------------------------------
// Fused eval+march. 64 rows = 32 rays/block: rows 0-31 = s-points, rows
// 32-63 = e-points. r22 structure verbatim (parallel embed, 4x1 tile,
// march tail on threads 0-31).
// ---------------------------------------------------------------------------
__global__ __launch_bounds__(1024, 1)
void eval_fused(EvalP P, int tstep)
{
  __shared__ __align__(16) unsigned short Ah[64 * SK];   // 40 KB
  __shared__ __align__(16) unsigned short Al[64 * SK];   // 40 KB
  __shared__ float enc[64 * 40];                         // 10 KB
  __shared__ float red[8 * 64];                          // 2 KB
  __shared__ float sdfv[64];
  const int WBA[8] = {0,16384,81920,147456,212992,294912,360448,425984};

  const int t = threadIdx.x;
  const int rayb = blockIdx.x * 32;

  // ---- embed part 1: normalized coords (192 threads, 64 rows x 3)
  if (t < 192) {
    int row = t / 3, c = t - row * 3;
    int idx = (row < 32) ? (rayb + row) : (NR + rayb + row - 32);
    float p = P.evalpts[3 * idx + c];
    enc[row * 40 + c] = ((p + 1.0f) * 0.5f) * 2.0f - 1.0f;
  }
  __syncthreads();
  // ---- embed part 2: 64 rows x 36 trig over all 1024 threads (exact
  // sinf/cosf; arg = xn * 2^lf — identical product to the serial version)
  for (int i = t; i < 64 * 36; i += 1024) {
    int row = i / 36, j = i - row * 36;
    int jj = (j < 18) ? j : j - 18;
    int c = jj % 3, lf = jj / 3;
    float arg = enc[row * 40 + c] * (float)(1 << lf);
    enc[row * 40 + 3 + j] = (j < 18) ? sinf(arg) : cosf(arg);
  }
  __syncthreads();

  // ---- scatter enc (bf16 hi/lo) to planes: k in [0,64) and [256,320)
  {
    char* ahp = (char*)Ah;
    char* alp = (char*)Al;
    int row = t >> 4, c4 = t & 15;   // 64 rows x 16 chunks of 4 k
    int sw = (row & 7) << 4;
    #pragma unroll
    for (int reg = 0; reg < 2; ++reg) {
      int koff = reg ? 256 : 0;
      #pragma unroll
      for (int e = 0; e < 4; e += 2) {
        int kl = c4 * 4 + e;
        float v0 = (kl     < 39) ? enc[row * 40 + kl]     : 0.0f;
        float v1 = (kl + 1 < 39) ? enc[row * 40 + kl + 1] : 0.0f;
        unsigned short h0 = f2bf(v0), h1 = f2bf(v1);
        unsigned short q0 = f2bf(v0 - bf2f(h0)), q1 = f2bf(v1 - bf2f(h1));
        int addr = row * SKB + (((koff + kl) * 2) ^ sw);
        *(unsigned int*)(ahp + addr) = (unsigned)h0 | ((unsigned)h1 << 16);
        *(unsigned int*)(alp + addr) = (unsigned)q0 | ((unsigned)q1 << 16);
      }
    }
  }
  __syncthreads();

  const int lane = t & 63, wv = t >> 6;   // 16 waves
  const int lq = lane >> 4, lr = lane & 15;
  const int cw = wv * 16;                 // wave owns 16 cols
  const char* ahc = (const char*)Ah;
  const int swA = (lr & 7) << 4;

  // ---- layers 0..7
  layer_bpre<2, 64>(P.WTi + 2 * (size_t)WBA[0], P.b[0], Ah, Al, lq, lr, cw, swA);
  #pragma unroll 1
  for (int l = 1; l < 8; ++l) {
    if (l == 4)
      layer_bpre<10, 320>(P.WTi + 2 * (size_t)WBA[4], P.b[4], Ah, Al, lq, lr, cw, swA);
    else
      layer_bpre<8, 256>(P.WTi + 2 * (size_t)WBA[l], P.b[l], Ah, Al, lq, lr, cw, swA);
  }

  // ---- layer 8: column 0 only; 8x32-k partition + part-ascending reduce
  {
    const char* alc = (const char*)Al;
    if (t < 512) {
      int row = t & 63, part = t >> 6;
      int sw = (row & 7) << 4;
      float s = 0.0f;
      #pragma unroll
      for (int c = 0; c < 4; ++c) {
        int k = part * 32 + c * 8;
        int addr = row * SKB + ((k * 2) ^ sw);
        short8v vh = *(const short8v*)(ahc + addr);
        short8v vl = *(const short8v*)(alc + addr);
        #pragma unroll
        for (int e = 0; e < 8; ++e) {
          float h = bf2f((unsigned short)vh[e]) + bf2f((unsigned short)vl[e]);
          s = fmaf(h, P.w8c[k + e], s);
        }
      }
      red[part * 64 + row] = s;
    }
    __syncthreads();
    if (t < 64) {
      float tot = P.b8[0];
      #pragma unroll
      for (int p = 0; p < 8; ++p) tot += red[p * 64 + t];
      sdfv[t] = tot;
    }
    __syncthreads();
  }

  // ---- march tail (march_kernel body verbatim; threads 0-31)
  if (t < 32) {
    int r = rayb + t;
    float tmn = P.tminA[r], tmx = P.tmaxA[r];
    float rs = sdfv[t], re = sdfv[32 + t];
    float ns, ne, as_, ae; int ms, me;
    if (tstep == 0) {
      ns = rs; ne = re; ms = 1; me = 1; as_ = tmn; ae = tmx;
    } else {
      ns = P.nextS[r]; ne = P.nextE[r];
      ns = P.mselS[r] ? rs : ns;       // selection deferred from step t-1
      ne = P.mselE[r] ? re : ne;
      ms = P.mcarS[r]; me = P.mcarE[r];
      as_ = P.accS[r]; ae = P.accE[r];
    }
    P.strack[r*8 + tstep] = rs;        // sdf_tracks[:, t] = unmasked s-eval
    float cs = (fabsf(ns) <= SDF_THR_C) ? 0.0f : ns;
    float ce = (fabsf(ne) <= SDF_THR_C) ? 0.0f : ne;
    ms = ms & ((fabsf(cs) > SDF_THR_C) ? 1 : 0);
    me = me & ((fabsf(ce) > SDF_THR_C) ? 1 : 0);
    as_ = fminf(as_ + cs, tmx);
    ae  = fminf(ae + ce, tmx);
    if (tstep < 7) {
      float ox = P.ray0[3*r], oy = P.ray0[3*r+1], oz = P.ray0[3*r+2];
      float dx = P.rdir[3*r], dy = P.rdir[3*r+1], dz = P.rdir[3*r+2];
      float px = ox + as_*dx, py = oy + as_*dy, pz = oz + as_*dz;
      float qx = ox + ae*dx,  qy = oy + ae*dy,  qz = oz + ae*dz;
      P.ptrack[r*24 + (tstep+1)*3 + 0] = px;
      P.ptrack[r*24 + (tstep+1)*3 + 1] = py;
      P.ptrack[r*24 + (tstep+1)*3 + 2] = pz;
      P.evalpts[3*r+0] = px; P.evalpts[3*r+1] = py; P.evalpts[3*r+2] = pz;
      P.evalpts[3*(NR+r)+0] = qx; P.evalpts[3*(NR+r)+1] = qy; P.evalpts[3*(NR+r)+2] = qz;
    }
    int ok = (as_ < ae) ? 1 : 0;
    P.mselS[r] = ms;       P.mselE[r] = me;       // pre-ok (select) masks
    P.mcarS[r] = ms & ok;  P.mcarE[r] = me & ok;  // carry masks
    P.nextS[r] = ns; P.nextE[r] = ne;
    P.accS[r] = as_; P.accE[r] = ae;
  }
}

// ---------------------------------------------------------------------------
// init: ray-AABB, initial points; block 0 also extracts w8 column 0
// ---------------------------------------------------------------------------
__global__ void init_kernel(const float* __restrict__ ray0, const float* __restrict__ rdir,
                            float* tminA, float* tmaxA, float* evalpts, float* ptrack,
                            const float* __restrict__ w8, float* __restrict__ w8c)
{
  if (blockIdx.x == 0) w8c[threadIdx.x] = w8[(size_t)threadIdx.x * 257];
  int r = blockIdx.x * 256 + threadIdx.x;
  if (r >= NR) return;
  float ox = ray0[3*r], oy = ray0[3*r+1], oz = ray0[3*r+2];
  float dx = rdir[3*r], dy = rdir[3*r+1], dz = rdir[3*r+2];
  float ix = 1.0f/dx, iy = 1.0f/dy, iz = 1.0f/dz;
  float t1x = (-1.0f - ox)*ix, t2x = (1.0f - ox)*ix;
  float t1y = (-1.0f - oy)*iy, t2y = (1.0f - oy)*iy;
  float t1z = (-1.0f - oz)*iz, t2z = (1.0f - oz)*iz;
  float tmn = fmaxf(fmaxf(fminf(t1x,t2x), fminf(t1y,t2y)), fminf(t1z,t2z));
  float tmx = fminf(fminf(fmaxf(t1x,t2x), fmaxf(t1y,t2y)), fmaxf(t1z,t2z));
  tmn = fmaxf(tmn, 0.0f);
  tminA[r] = tmn; tmaxA[r] = tmx;
  float px = ox + tmn*dx, py = oy + tmn*dy, pz = oz + tmn*dz;
  float qx = ox + tmx*dx, qy = oy + tmx*dy, qz = oz + tmx*dz;
  evalpts[3*r+0] = px; evalpts[3*r+1] = py; evalpts[3*r+2] = pz;
  evalpts[3*(NR+r)+0] = qx; evalpts[3*(NR+r)+1] = qy; evalpts[3*(NR+r)+2] = qz;
  ptrack[r*24+0] = px; ptrack[r*24+1] = py; ptrack[r*24+2] = pz;
}

// ---------------------------------------------------------------------------
// finalize: outputs
// ---------------------------------------------------------------------------
__global__ void finalize_kernel(const float* __restrict__ ray0, const float* __restrict__ rdir,
                                const float* __restrict__ frand, const int* __restrict__ pick,
                                const float* __restrict__ strack, const float* __restrict__ ptrack,
                                const float* __restrict__ accE,
                                const float* __restrict__ tminA, const float* __restrict__ tmaxA,
                                float* __restrict__ out)
{
  int r = blockIdx.x * 256 + threadIdx.x;
  if (r < NR) {
    float tmn = tminA[r], tmx = tmaxA[r];
    float sum = 0.f;
    #pragma unroll
    for (int tt = 0; tt < 8; ++tt) sum += strack[r*8 + tt];
    out[OUT_DPRED + r] = fminf(sum + tmn, tmx);
    float last = strack[r*8 + 7];
    out[OUT_SDFL + r] = last;
    out[OUT_FIN + r] = (fabsf(last) < 0.0015625f) ? 1.0f : 0.0f;
    float du = fminf(1.5f * accE[r], tmx);
    float fr = frand[r];
    float dsm = (1.0f - fr) * du + fr * tmn;
    float ox = ray0[3*r], oy = ray0[3*r+1], oz = ray0[3*r+2];
    float dx = rdir[3*r], dy = rdir[3*r+1], dz = rdir[3*r+2];
    int o2 = OUT_SAMP + 98304 + 3*r;
    out[o2+0] = ox + dsm*dx;
    out[o2+1] = oy + dsm*dy;
    out[o2+2] = oz + dsm*dz;
  }
  if (r < NPICK) {
    int ray = pick[r];
    #pragma unroll
    for (int i = 0; i < 24; ++i)
      out[OUT_SAMP + r*24 + i] = ptrack[ray*24 + i];
  }
}

// ---------------------------------------------------------------------------
extern "C" void kernel_launch(void* const* d_in, const int* in_sizes, int n_in,
                              void* d_out, int out_size, void* d_ws, size_t ws_size,
                              hipStream_t stream)
{
  const float* ray0  = (const float*)d_in[0];
  const float* rdir  = (const float*)d_in[1];
  const float* frand = (const float*)d_in[2];
  const int*   pick  = (const int*)d_in[3];
  Wptrs wp;
  EvalP ep;
  for (int i = 0; i < 8; ++i) {
    wp.w[i] = (const float*)d_in[4 + 2*i];
    ep.b[i] = (const float*)d_in[5 + 2*i];
  }
  const float* w8 = (const float*)d_in[20];
  ep.b8 = (const float*)d_in[21];
  ep.ray0 = ray0; ep.rdir = rdir;

  float* ws = (float*)d_ws;
  float* evalpts = ws;                 // 49152
  float* tminA   = evalpts + 49152;
  float* tmaxA   = tminA + 8192;
  float* nextS   = tmaxA + 8192;
  float* nextE   = nextS + 8192;
  float* accS    = nextE + 8192;
  float* accE    = accS + 8192;
  float* strack  = accE + 8192;        // 65536
  float* ptrack  = strack + 65536;     // 196608
  int*   mselS   = (int*)(ptrack + 196608);
  int*   mselE   = mselS + 8192;
  int*   mcarS   = mselE + 8192;
  int*   mcarE   = mcarS + 8192;
  float* w8c     = (float*)(mcarE + 8192);
  unsigned short* WTi = (unsigned short*)(w8c + 256);   // 983040 shorts fragment-major
  ep.WTi = WTi; ep.w8c = w8c;
  ep.tminA = tminA; ep.tmaxA = tmaxA;
  ep.nextS = nextS; ep.nextE = nextE;
  ep.mselS = mselS; ep.mselE = mselE; ep.mcarS = mcarS; ep.mcarE = mcarE;
  ep.accS = accS; ep.accE = accE;
  ep.strack = strack; ep.ptrack = ptrack; ep.evalpts = evalpts;
  float* out = (float*)d_out;

  prep_transpose<<<120, 256, 0, stream>>>(wp, WTi);
  init_kernel<<<NR/256, 256, 0, stream>>>(ray0, rdir, tminA, tmaxA, evalpts, ptrack, w8, w8c);
  for (int t = 0; t < 8; ++t)
    eval_fused<<<NR/32, 1024, 0, stream>>>(ep, t);
  finalize_kernel<<<NR/256, 256, 0, stream>>>(ray0, rdir, frand, pick,
                                              strack, ptrack, accE, tminA, tmaxA, out);
}